// Round 3
// baseline (384.857 us; speedup 1.0000x reference)
//
#include <hip/hip_runtime.h>
#include <hip/hip_bf16.h>
#include <stdint.h>

#define D_MODEL 1024
#define HIDDEN  2048
#define N_EXP   8
#define T_TOK   8192
#define MAXPOS  17408   // 16384 assignments + 8*128 padding
#define ROWTILES (MAXPOS/128)

typedef __attribute__((ext_vector_type(4))) float f32x4;
typedef __attribute__((ext_vector_type(8))) short short8v;

__device__ __forceinline__ unsigned short f2bf(float f) {
    union { float f; unsigned int u; } v; v.f = f;
    unsigned int u = v.u;
    unsigned int r = (u + 0x7fffu + ((u >> 16) & 1u)) >> 16;  // RNE
    return (unsigned short)r;
}
__device__ __forceinline__ float bf2f(unsigned short s) {
    union { unsigned int u; float f; } v; v.u = ((unsigned int)s) << 16;
    return v.f;
}

__device__ __forceinline__ void gload_lds16(const void* g, void* l) {
    __builtin_amdgcn_global_load_lds(
        reinterpret_cast<const __attribute__((address_space(1))) unsigned int*>(
            reinterpret_cast<uintptr_t>(g)),
        reinterpret_cast<__attribute__((address_space(3))) unsigned int*>(
            (uint32_t)reinterpret_cast<uintptr_t>(l)),
        16, 0, 0);
}

// ---------------- fused RMSNorm + gate: one WAVE per token, no atomics ----------------
__global__ void rms_gate_kernel(const float* __restrict__ x,
                                const float* __restrict__ nw,
                                const float* __restrict__ gw,
                                unsigned short* __restrict__ tb,   // bf16 t [T][D]
                                int* __restrict__ tok_e,           // [T][2]
                                float* __restrict__ tok_w) {       // [T][2]
    const int wave = threadIdx.x >> 6;
    const int lane = threadIdx.x & 63;
    const int t = blockIdx.x * 4 + wave;

    const float4* xr = (const float4*)(x + (size_t)t * D_MODEL);
    const float4* wr = (const float4*)nw;
    float4 xv[4], wv[4];
    #pragma unroll
    for (int j = 0; j < 4; j++) {
        xv[j] = xr[j * 64 + lane];
        wv[j] = wr[j * 64 + lane];
    }

    float ssq = 0.0f;
    #pragma unroll
    for (int j = 0; j < 4; j++)
        ssq += xv[j].x * xv[j].x + xv[j].y * xv[j].y + xv[j].z * xv[j].z + xv[j].w * xv[j].w;
    #pragma unroll
    for (int off = 32; off; off >>= 1) ssq += __shfl_xor(ssq, off);
    const float scale = rsqrtf(ssq * (1.0f / D_MODEL) + 1e-6f);

    float4 tn[4];
    #pragma unroll
    for (int j = 0; j < 4; j++) {
        tn[j].x = xv[j].x * wv[j].x * scale;
        tn[j].y = xv[j].y * wv[j].y * scale;
        tn[j].z = xv[j].z * wv[j].z * scale;
        tn[j].w = xv[j].w * wv[j].w * scale;
    }

    ushort4* tw = (ushort4*)(tb + (size_t)t * D_MODEL);
    #pragma unroll
    for (int j = 0; j < 4; j++) {
        ushort4 o;
        o.x = f2bf(tn[j].x); o.y = f2bf(tn[j].y);
        o.z = f2bf(tn[j].z); o.w = f2bf(tn[j].w);
        tw[j * 64 + lane] = o;
    }

    float d[8];
    #pragma unroll
    for (int e = 0; e < 8; e++) {
        d[e] = 0.0f;
        #pragma unroll
        for (int j = 0; j < 4; j++) {
            float4 g = ((const float4*)(gw + e * D_MODEL))[j * 64 + lane];
            d[e] += tn[j].x * g.x + tn[j].y * g.y + tn[j].z * g.z + tn[j].w * g.w;
        }
    }
    #pragma unroll
    for (int e = 0; e < 8; e++) {
        #pragma unroll
        for (int off = 32; off; off >>= 1) d[e] += __shfl_xor(d[e], off);
    }

    if (lane == 0) {
        int i0 = 0;
        #pragma unroll
        for (int e = 1; e < 8; e++) if (d[e] > d[i0]) i0 = e;   // ties -> lowest idx
        int i1 = -1;
        #pragma unroll
        for (int e = 0; e < 8; e++)
            if (e != i0 && (i1 < 0 || d[e] > d[i1])) i1 = e;
        float e1 = expf(d[i1] - d[i0]);
        float w0 = 1.0f / (1.0f + e1);
        ((int2*)tok_e)[t]   = make_int2(i0, i1);
        ((float2*)tok_w)[t] = make_float2(w0, e1 * w0);
    }
}

// ---------------- histogram: LDS-local, 8 global atomics per block ----------------
__global__ void hist_kernel(const int* __restrict__ tok_e, int* __restrict__ counts) {
    __shared__ int lh[8];
    if (threadIdx.x < 8) lh[threadIdx.x] = 0;
    __syncthreads();
    int i = blockIdx.x * 512 + threadIdx.x;
    atomicAdd(&lh[tok_e[i]], 1);
    atomicAdd(&lh[tok_e[i + 256]], 1);
    __syncthreads();
    if (threadIdx.x < 8) atomicAdd(&counts[threadIdx.x], lh[threadIdx.x]);
}

// ---------------- padded-offset scan + perm zero-fill ----------------
__global__ void scan_fill_kernel(int* __restrict__ perm_tok,
                                 const int* __restrict__ counts,
                                 int* __restrict__ poff, int* __restrict__ pos_ctr) {
    int i = blockIdx.x * 256 + threadIdx.x;
    if (i < MAXPOS) perm_tok[i] = 0;
    if (blockIdx.x == 0 && threadIdx.x == 0) {
        int acc = 0; poff[0] = 0;
        #pragma unroll
        for (int e = 0; e < 8; e++) {
            pos_ctr[e] = 0;
            acc += (counts[e] + 127) & ~127;
            poff[e + 1] = acc;
        }
    }
}

// ---------------- scatter: block-level LDS reservation + inverse map ----------------
__global__ void scatter_kernel(const int* __restrict__ tok_e,
                               const int* __restrict__ poff, int* __restrict__ pos_ctr,
                               int* __restrict__ perm_tok, int* __restrict__ tok_pos) {
    __shared__ int lh[8], lbase[8];
    if (threadIdx.x < 8) lh[threadIdx.x] = 0;
    __syncthreads();
    int t = blockIdx.x * 256 + threadIdx.x;
    int2 ee = ((const int2*)tok_e)[t];
    int p0 = atomicAdd(&lh[ee.x], 1);
    int p1 = atomicAdd(&lh[ee.y], 1);
    __syncthreads();
    if (threadIdx.x < 8) lbase[threadIdx.x] = atomicAdd(&pos_ctr[threadIdx.x], lh[threadIdx.x]);
    __syncthreads();
    int q0 = poff[ee.x] + lbase[ee.x] + p0;
    int q1 = poff[ee.y] + lbase[ee.y] + p1;
    perm_tok[q0] = t;
    perm_tok[q1] = t;
    ((int2*)tok_pos)[t] = make_int2(q0, q1);
}

// ---------------- fp32 -> bf16 weight convert ----------------
__global__ void cvt_bf16_kernel(const float4* __restrict__ in,
                                ushort4* __restrict__ outp, int n4) {
    int i = blockIdx.x * blockDim.x + threadIdx.x;
    if (i >= n4) return;
    float4 v = in[i];
    ushort4 o; o.x = f2bf(v.x); o.y = f2bf(v.y); o.z = f2bf(v.z); o.w = f2bf(v.w);
    outp[i] = o;
}

// ---------------- grouped GEMM (m97 structure: 128x128 tile, BK=64) ----------------
// MODE 1: Hout = gelu(A_gathered @ W^T + b) -> bf16       (K=1024, N=2048)
// MODE 2: Obuf = A @ W^T + b -> bf16 per-assignment rows  (K=2048, N=1024)
template <int MODE, int K, int N>
__global__ __launch_bounds__(256) void moe_gemm_kernel(
                                const unsigned short* __restrict__ A,
                                const unsigned short* __restrict__ W,
                                const float* __restrict__ bias,
                                const int* __restrict__ perm_tok,
                                const int* __restrict__ poff,
                                unsigned short* __restrict__ Cout) {
    constexpr int NT = N / 128;
    __shared__ short lds[17408];          // staging 32KB; epilogue C-tile [128][136]
    short* Asm = lds;
    short* Bsm = lds + 8192;

    // T1: XCD-aware swizzle (grid % 8 == 0 for both instantiations)
    const int nwg = gridDim.x;
    const int cpx = nwg >> 3;
    const int bid = (int)blockIdx.x;
    const int swz = (bid & 7) * cpx + (bid >> 3);

    const int rt = swz / NT, nt = swz % NT;
    const int row_base = rt * 128;
    if (row_base >= poff[8]) return;
    int e = 0;
    while (poff[e + 1] <= row_base) ++e;
    const int n0 = nt * 128;

    const int tid = threadIdx.x;
    const int wave = tid >> 6, lane = tid & 63;
    const int colb = (tid & 7) * 16;
    const int wr = wave >> 1, wc = wave & 1;

    size_t aoff[4], boff[4];
    #pragma unroll
    for (int i = 0; i < 4; i++) {
        int r = row_base + i * 32 + (tid >> 3);
        int arow = (MODE == 1) ? perm_tok[r] : r;
        aoff[i] = (size_t)arow * (K * 2);
        int brow = n0 + i * 32 + (tid >> 3);
        boff[i] = ((size_t)e * N + brow) * (size_t)(K * 2);
    }
    const char* Ab = (const char*)A;
    const char* Wb = (const char*)W;

    f32x4 acc[4][4];
    #pragma unroll
    for (int mi = 0; mi < 4; mi++)
        #pragma unroll
        for (int ni = 0; ni < 4; ni++) acc[mi][ni] = (f32x4)(0.0f);

    for (int k0b = 0; k0b < K * 2; k0b += 128) {
        #pragma unroll
        for (int i = 0; i < 4; i++) {
            gload_lds16(Ab + aoff[i] + k0b + colb, (char*)Asm + i * 4096 + wave * 1024);
            gload_lds16(Wb + boff[i] + k0b + colb, (char*)Bsm + i * 4096 + wave * 1024);
        }
        __syncthreads();
        #pragma unroll
        for (int kk = 0; kk < 2; kk++) {
            short8v af[4], bf[4];
            #pragma unroll
            for (int mi = 0; mi < 4; mi++)
                af[mi] = *(const short8v*)&Asm[(wr * 64 + mi * 16 + (lane & 15)) * 64 + kk * 32 + (lane >> 4) * 8];
            #pragma unroll
            for (int ni = 0; ni < 4; ni++)
                bf[ni] = *(const short8v*)&Bsm[(wc * 64 + ni * 16 + (lane & 15)) * 64 + kk * 32 + (lane >> 4) * 8];
            #pragma unroll
            for (int mi = 0; mi < 4; mi++)
                #pragma unroll
                for (int ni = 0; ni < 4; ni++)
                    acc[mi][ni] = __builtin_amdgcn_mfma_f32_16x16x32_bf16(af[mi], bf[ni], acc[mi][ni], 0, 0, 0);
        }
        __syncthreads();
    }

    // ---- epilogue: acc -> (bias, act, bf16) -> LDS [128][136] -> coalesced stores ----
    #pragma unroll
    for (int mi = 0; mi < 4; mi++) {
        #pragma unroll
        for (int ni = 0; ni < 4; ni++) {
            int lc = wc * 64 + ni * 16 + (lane & 15);
            float bv = bias[e * N + n0 + lc];
            #pragma unroll
            for (int j = 0; j < 4; j++) {
                int lr = wr * 64 + mi * 16 + (lane >> 4) * 4 + j;
                float v = acc[mi][ni][j] + bv;
                if (MODE == 1)
                    v = 0.5f * v * (1.0f + erff(v * 0.70710678118654752f));  // exact gelu
                lds[lr * 136 + lc] = (short)f2bf(v);
            }
        }
    }
    __syncthreads();
    {
        const int rr = tid >> 4;        // 0..15
        const int cc = tid & 15;        // 16B chunks within 256B row
        #pragma unroll
        for (int p = 0; p < 8; p++) {
            int lr = p * 16 + rr;
            short8v vv = *(const short8v*)&lds[lr * 136 + cc * 8];
            *(short8v*)(Cout + (size_t)(row_base + lr) * N + n0 + cc * 8) = vv;
        }
    }
}

// ---------------- combine: out = x + w0*O[p0] + w1*O[p1] ----------------
__global__ void combine_kernel(const float* __restrict__ x,
                               const int* __restrict__ tok_pos,
                               const float* __restrict__ tok_w,
                               const unsigned short* __restrict__ obuf,
                               float* __restrict__ out) {
    const int wave = threadIdx.x >> 6;
    const int lane = threadIdx.x & 63;
    const int t = blockIdx.x * 4 + wave;
    int2 pp = ((const int2*)tok_pos)[t];
    float2 ww = ((const float2*)tok_w)[t];
    const float4* xr = (const float4*)(x + (size_t)t * D_MODEL);
    float4* orow = (float4*)(out + (size_t)t * D_MODEL);
    const short4* o0 = (const short4*)(obuf + (size_t)pp.x * D_MODEL);
    const short4* o1 = (const short4*)(obuf + (size_t)pp.y * D_MODEL);
    #pragma unroll
    for (int j = 0; j < 4; j++) {
        int idx = j * 64 + lane;
        float4 xv = xr[idx];
        short4 a = o0[idx];
        short4 b = o1[idx];
        float4 r;
        r.x = xv.x + ww.x * bf2f((unsigned short)a.x) + ww.y * bf2f((unsigned short)b.x);
        r.y = xv.y + ww.x * bf2f((unsigned short)a.y) + ww.y * bf2f((unsigned short)b.y);
        r.z = xv.z + ww.x * bf2f((unsigned short)a.z) + ww.y * bf2f((unsigned short)b.z);
        r.w = xv.w + ww.x * bf2f((unsigned short)a.w) + ww.y * bf2f((unsigned short)b.w);
        orow[idx] = r;
    }
}

// ---------------- launch ----------------
extern "C" void kernel_launch(void* const* d_in, const int* in_sizes, int n_in,
                              void* d_out, int out_size, void* d_ws, size_t ws_size,
                              hipStream_t stream) {
    const float* x  = (const float*)d_in[0];
    const float* nw = (const float*)d_in[1];
    const float* gw = (const float*)d_in[2];
    const float* w1 = (const float*)d_in[3];
    const float* b1 = (const float*)d_in[4];
    const float* w2 = (const float*)d_in[5];
    const float* b2 = (const float*)d_in[6];
    float* out = (float*)d_out;
    char* ws = (char*)d_ws;

    size_t off = 0;
    unsigned short* tb   = (unsigned short*)(ws + off); off += (size_t)T_TOK * D_MODEL * 2;          // 16 MiB
    unsigned short* w1b  = (unsigned short*)(ws + off); off += (size_t)N_EXP * HIDDEN * D_MODEL * 2; // 32 MiB
    unsigned short* w2b  = (unsigned short*)(ws + off); off += (size_t)N_EXP * D_MODEL * HIDDEN * 2; // 32 MiB
    unsigned short* h    = (unsigned short*)(ws + off); off += (size_t)MAXPOS * HIDDEN * 2;          // 68 MiB
    unsigned short* obuf = (unsigned short*)(ws + off); off += (size_t)MAXPOS * D_MODEL * 2;         // 34 MiB
    int*   perm_tok = (int*)(ws + off);   off += MAXPOS * 4;
    int*   tok_e    = (int*)(ws + off);   off += T_TOK * 2 * 4;
    float* tok_w    = (float*)(ws + off); off += T_TOK * 2 * 4;
    int*   tok_pos  = (int*)(ws + off);   off += T_TOK * 2 * 4;
    int*   meta     = (int*)(ws + off);   // counts[8] | pos_ctr[8] | poff[9]
    int* counts  = meta;
    int* pos_ctr = meta + 8;
    int* poff    = meta + 16;

    hipMemsetAsync(meta, 0, 32, stream);                                   // zero counts

    rms_gate_kernel<<<T_TOK / 4, 256, 0, stream>>>(x, nw, gw, tb, tok_e, tok_w);

    const int n4 = N_EXP * HIDDEN * D_MODEL / 4;
    cvt_bf16_kernel<<<n4 / 256, 256, 0, stream>>>((const float4*)w1, (ushort4*)w1b, n4);
    cvt_bf16_kernel<<<n4 / 256, 256, 0, stream>>>((const float4*)w2, (ushort4*)w2b, n4);

    hist_kernel<<<32, 256, 0, stream>>>(tok_e, counts);
    scan_fill_kernel<<<MAXPOS / 256, 256, 0, stream>>>(perm_tok, counts, poff, pos_ctr);
    scatter_kernel<<<T_TOK / 256, 256, 0, stream>>>(tok_e, poff, pos_ctr, perm_tok, tok_pos);

    moe_gemm_kernel<1, D_MODEL, HIDDEN><<<ROWTILES * (HIDDEN / 128), 256, 0, stream>>>(
        tb, w1b, b1, perm_tok, poff, h);
    moe_gemm_kernel<2, HIDDEN, D_MODEL><<<ROWTILES * (D_MODEL / 128), 256, 0, stream>>>(
        h, w2b, b2, perm_tok, poff, obuf);

    combine_kernel<<<T_TOK / 4, 256, 0, stream>>>(x, tok_pos, tok_w, obuf, out);
}

// Round 7
// 381.829 us; speedup vs baseline: 1.0079x; 1.0079x over previous
//
#include <hip/hip_runtime.h>
#include <hip/hip_bf16.h>
#include <stdint.h>

#define D_MODEL 1024
#define HIDDEN  2048
#define N_EXP   8
#define T_TOK   8192
#define BM      256
#define MAXPOS  (16384 + N_EXP * BM)   // 18432
#define ROWT    (MAXPOS / BM)          // 72

typedef __attribute__((ext_vector_type(4))) float f32x4;
typedef __attribute__((ext_vector_type(8))) short short8v;

__device__ __forceinline__ unsigned short f2bf(float f) {
    union { float f; unsigned int u; } v; v.f = f;
    unsigned int u = v.u;
    unsigned int r = (u + 0x7fffu + ((u >> 16) & 1u)) >> 16;  // RNE
    return (unsigned short)r;
}
__device__ __forceinline__ float bf2f(unsigned short s) {
    union { unsigned int u; float f; } v; v.u = ((unsigned int)s) << 16;
    return v.f;
}

__device__ __forceinline__ void gload_lds16(const void* g, void* l) {
    __builtin_amdgcn_global_load_lds(
        reinterpret_cast<const __attribute__((address_space(1))) unsigned int*>(
            reinterpret_cast<uintptr_t>(g)),
        reinterpret_cast<__attribute__((address_space(3))) unsigned int*>(
            (uint32_t)reinterpret_cast<uintptr_t>(l)),
        16, 0, 0);
}

// ---------------- fused RMSNorm + gate: one WAVE per token, no atomics ----------------
__global__ void rms_gate_kernel(const float* __restrict__ x,
                                const float* __restrict__ nw,
                                const float* __restrict__ gw,
                                unsigned short* __restrict__ tb,
                                int* __restrict__ tok_e,
                                float* __restrict__ tok_w) {
    const int wave = threadIdx.x >> 6;
    const int lane = threadIdx.x & 63;
    const int t = blockIdx.x * 4 + wave;

    const float4* xr = (const float4*)(x + (size_t)t * D_MODEL);
    const float4* wr = (const float4*)nw;
    float4 xv[4], wv[4];
    #pragma unroll
    for (int j = 0; j < 4; j++) {
        xv[j] = xr[j * 64 + lane];
        wv[j] = wr[j * 64 + lane];
    }

    float ssq = 0.0f;
    #pragma unroll
    for (int j = 0; j < 4; j++)
        ssq += xv[j].x * xv[j].x + xv[j].y * xv[j].y + xv[j].z * xv[j].z + xv[j].w * xv[j].w;
    #pragma unroll
    for (int off = 32; off; off >>= 1) ssq += __shfl_xor(ssq, off);
    const float scale = rsqrtf(ssq * (1.0f / D_MODEL) + 1e-6f);

    float4 tn[4];
    #pragma unroll
    for (int j = 0; j < 4; j++) {
        tn[j].x = xv[j].x * wv[j].x * scale;
        tn[j].y = xv[j].y * wv[j].y * scale;
        tn[j].z = xv[j].z * wv[j].z * scale;
        tn[j].w = xv[j].w * wv[j].w * scale;
    }

    ushort4* tw = (ushort4*)(tb + (size_t)t * D_MODEL);
    #pragma unroll
    for (int j = 0; j < 4; j++) {
        ushort4 o;
        o.x = f2bf(tn[j].x); o.y = f2bf(tn[j].y);
        o.z = f2bf(tn[j].z); o.w = f2bf(tn[j].w);
        tw[j * 64 + lane] = o;
    }

    float d[8];
    #pragma unroll
    for (int e = 0; e < 8; e++) {
        d[e] = 0.0f;
        #pragma unroll
        for (int j = 0; j < 4; j++) {
            float4 g = ((const float4*)(gw + e * D_MODEL))[j * 64 + lane];
            d[e] += tn[j].x * g.x + tn[j].y * g.y + tn[j].z * g.z + tn[j].w * g.w;
        }
    }
    #pragma unroll
    for (int e = 0; e < 8; e++) {
        #pragma unroll
        for (int off = 32; off; off >>= 1) d[e] += __shfl_xor(d[e], off);
    }

    if (lane == 0) {
        int i0 = 0;
        #pragma unroll
        for (int e = 1; e < 8; e++) if (d[e] > d[i0]) i0 = e;
        int i1 = -1;
        #pragma unroll
        for (int e = 0; e < 8; e++)
            if (e != i0 && (i1 < 0 || d[e] > d[i1])) i1 = e;
        float e1 = expf(d[i1] - d[i0]);
        float w0 = 1.0f / (1.0f + e1);
        ((int2*)tok_e)[t]   = make_int2(i0, i1);
        ((float2*)tok_w)[t] = make_float2(w0, e1 * w0);
    }
}

// ---------------- histogram ----------------
__global__ void hist_kernel(const int* __restrict__ tok_e, int* __restrict__ counts) {
    __shared__ int lh[8];
    if (threadIdx.x < 8) lh[threadIdx.x] = 0;
    __syncthreads();
    int i = blockIdx.x * 512 + threadIdx.x;
    atomicAdd(&lh[tok_e[i]], 1);
    atomicAdd(&lh[tok_e[i + 256]], 1);
    __syncthreads();
    if (threadIdx.x < 8) atomicAdd(&counts[threadIdx.x], lh[threadIdx.x]);
}

// ---------------- padded-offset scan + perm zero-fill (pad to 256) ----------------
__global__ void scan_fill_kernel(int* __restrict__ perm_tok,
                                 const int* __restrict__ counts,
                                 int* __restrict__ poff, int* __restrict__ pos_ctr) {
    int i = blockIdx.x * 256 + threadIdx.x;
    if (i < MAXPOS) perm_tok[i] = 0;
    if (blockIdx.x == 0 && threadIdx.x == 0) {
        int acc = 0; poff[0] = 0;
        #pragma unroll
        for (int e = 0; e < 8; e++) {
            pos_ctr[e] = 0;
            acc += (counts[e] + (BM - 1)) & ~(BM - 1);
            poff[e + 1] = acc;
        }
    }
}

// ---------------- scatter with inverse map ----------------
__global__ void scatter_kernel(const int* __restrict__ tok_e,
                               const int* __restrict__ poff, int* __restrict__ pos_ctr,
                               int* __restrict__ perm_tok, int* __restrict__ tok_pos) {
    __shared__ int lh[8], lbase[8];
    if (threadIdx.x < 8) lh[threadIdx.x] = 0;
    __syncthreads();
    int t = blockIdx.x * 256 + threadIdx.x;
    int2 ee = ((const int2*)tok_e)[t];
    int p0 = atomicAdd(&lh[ee.x], 1);
    int p1 = atomicAdd(&lh[ee.y], 1);
    __syncthreads();
    if (threadIdx.x < 8) lbase[threadIdx.x] = atomicAdd(&pos_ctr[threadIdx.x], lh[threadIdx.x]);
    __syncthreads();
    int q0 = poff[ee.x] + lbase[ee.x] + p0;
    int q1 = poff[ee.y] + lbase[ee.y] + p1;
    perm_tok[q0] = t;
    perm_tok[q1] = t;
    ((int2*)tok_pos)[t] = make_int2(q0, q1);
}

// ---------------- fp32 -> bf16 weight convert ----------------
__global__ void cvt_bf16_kernel(const float4* __restrict__ in,
                                ushort4* __restrict__ outp, int n4) {
    int i = blockIdx.x * blockDim.x + threadIdx.x;
    if (i >= n4) return;
    float4 v = in[i];
    ushort4 o; o.x = f2bf(v.x); o.y = f2bf(v.y); o.z = f2bf(v.z); o.w = f2bf(v.w);
    outp[i] = o;
}

// ===== grouped GEMM: 256x256 tile, BK=64, 8 waves, 2-phase (T3 minimum recipe) =====
// MODE 1: Hout = gelu(A_gathered @ W^T + b) -> bf16   (K=1024, N=2048)
// MODE 2: Obuf = A @ W^T + b -> bf16                  (K=2048, N=1024)
// LDS: buf{0,1} x { A [256 rows][128B], B [256 rows][128B] }, 32KiB each region.
// st_16x32 swizzle: LDS(r, cb) holds global col byte cb ^ ((r&4)<<3); applied by
// pre-swizzling the per-lane GLOBAL source (cswz) and the ds_read col (csw0/1).

#define STAGE_ALL(BUF, K0) do { \
    gload_lds16(gb[0][0] + (K0), lds + (BUF)*65536 + 32768 + (w*16)*128); \
    gload_lds16(gb[0][1] + (K0), lds + (BUF)*65536 + 32768 + (w*16 + 8)*128); \
    gload_lds16(gb[1][0] + (K0), lds + (BUF)*65536 + 32768 + (128 + w*16)*128); \
    gload_lds16(gb[1][1] + (K0), lds + (BUF)*65536 + 32768 + (128 + w*16 + 8)*128); \
    gload_lds16(ga[0] + (K0), lds + (BUF)*65536 + rsA[0]*128); \
    gload_lds16(ga[1] + (K0), lds + (BUF)*65536 + rsA[1]*128); \
    gload_lds16(ga[2] + (K0), lds + (BUF)*65536 + rsA[2]*128); \
    gload_lds16(ga[3] + (K0), lds + (BUF)*65536 + rsA[3]*128); \
} while (0)

template <int MODE, int K, int N>
__global__ __launch_bounds__(512) void moe_gemm_kernel(
        const unsigned short* __restrict__ A,
        const unsigned short* __restrict__ W,
        const float* __restrict__ bias,
        const int* __restrict__ perm_tok,
        const int* __restrict__ poff,
        unsigned short* __restrict__ Cout) {
    constexpr int NT  = N / 256;
    constexpr int K2  = K * 2;
    constexpr int NTK = K / 64;
    __shared__ __align__(16) char lds[131072];

    const int nwg = gridDim.x;
    const int cpx = nwg >> 3;
    const int bid = (int)blockIdx.x;
    const int swzb = (bid & 7) * cpx + (bid >> 3);
    const int rt = swzb / NT, nt = swzb % NT;
    const int row_base = rt * BM;
    if (row_base >= poff[8]) return;
    int e = 0;
    while (poff[e + 1] <= row_base) ++e;
    const int n0 = nt * 256;

    const int tid = threadIdx.x;
    const int w = tid >> 6, l = tid & 63;
    const int wr = w >> 2, wc = w & 3;
    const int cswz = ((l & 7) * 16) ^ (l & 32);   // inverse-swizzled source col byte

    const char* Ab = (const char*)A;
    const char* Wb = (const char*)W;
    const char* ga[4];
    const char* gb[2][2];
    int rsA[4];
    #pragma unroll
    for (int s = 0; s < 4; s++) {
        int rstart = (w < 4) ? (s * 32 + w * 8) : (128 + s * 32 + (w - 4) * 8);
        rsA[s] = rstart;
        int r = row_base + rstart + (l >> 3);
        size_t arow = (MODE == 1) ? (size_t)perm_tok[r] : (size_t)r;
        ga[s] = Ab + arow * K2 + cswz;
    }
    #pragma unroll
    for (int g = 0; g < 2; g++)
        #pragma unroll
        for (int j = 0; j < 2; j++) {
            int r = g * 128 + w * 16 + j * 8 + (l >> 3);
            gb[g][j] = Wb + ((size_t)e * N + n0 + r) * K2 + cswz;
        }

    // ds_read addressing (swizzled read side)
    const int aRow = (wr * 128 + (l & 15)) * 128;
    const int bRow = (wc * 64 + (l & 15)) * 128;
    const int csw0 = (((l >> 4) * 16)      ) ^ ((l & 4) << 3);
    const int csw1 = (64 + ((l >> 4) * 16) ) ^ ((l & 4) << 3);

    f32x4 acc[8][4];
    #pragma unroll
    for (int mi = 0; mi < 8; mi++)
        #pragma unroll
        for (int ni = 0; ni < 4; ni++) acc[mi][ni] = (f32x4)(0.0f);
    short8v bfr[4][2];

    // prologue: stage tile 0 -> buf0; full drain before first reads
    STAGE_ALL(0, 0);
    __syncthreads();

    int cur = 0;
    #pragma unroll 1
    for (int t = 0; t < NTK; ++t) {
        // issue next-tile stages FIRST (overlap with compute below)
        if (t + 1 < NTK) {
            const int kn = (t + 1) * 128;
            STAGE_ALL(1 - cur, kn);
        }
        // compute buf[cur]
        const char* BL = lds + cur * 65536 + 32768 + bRow;
        #pragma unroll
        for (int ni = 0; ni < 4; ni++) {
            bfr[ni][0] = *(const short8v*)(BL + ni * 2048 + csw0);
            bfr[ni][1] = *(const short8v*)(BL + ni * 2048 + csw1);
        }
        const char* AL = lds + cur * 65536 + aRow;
        #pragma unroll
        for (int q = 0; q < 4; q++) {
            short8v af0 = *(const short8v*)(AL + q * 4096 + csw0);
            short8v af1 = *(const short8v*)(AL + q * 4096 + csw1);
            short8v af2 = *(const short8v*)(AL + q * 4096 + 2048 + csw0);
            short8v af3 = *(const short8v*)(AL + q * 4096 + 2048 + csw1);
            #pragma unroll
            for (int ni = 0; ni < 4; ni++) {
                acc[2*q][ni]   = __builtin_amdgcn_mfma_f32_16x16x32_bf16(af0, bfr[ni][0], acc[2*q][ni],   0, 0, 0);
                acc[2*q][ni]   = __builtin_amdgcn_mfma_f32_16x16x32_bf16(af1, bfr[ni][1], acc[2*q][ni],   0, 0, 0);
                acc[2*q+1][ni] = __builtin_amdgcn_mfma_f32_16x16x32_bf16(af2, bfr[ni][0], acc[2*q+1][ni], 0, 0, 0);
                acc[2*q+1][ni] = __builtin_amdgcn_mfma_f32_16x16x32_bf16(af3, bfr[ni][1], acc[2*q+1][ni], 0, 0, 0);
            }
        }
        __syncthreads();   // drains vmcnt(0)+lgkmcnt(0): next buf ready, this buf free
        cur ^= 1;
    }

    // ---- epilogue, two column-half passes (R6 BUG FIX: 256-wide tile cannot use
    // stride-136 LDS bounce in one pass; cols >=136 collided with the next row) ----
    short* sl = (short*)lds;
    #pragma unroll
    for (int h = 0; h < 2; h++) {
        if ((wc >> 1) == h) {   // waves owning cols [h*128, h*128+128) write this pass
            #pragma unroll
            for (int mi = 0; mi < 8; mi++) {
                #pragma unroll
                for (int ni = 0; ni < 4; ni++) {
                    int gcol = wc * 64 + ni * 16 + (l & 15);       // col in [0,256)
                    int lc   = gcol - h * 128;                     // local col [0,128)
                    float bv = bias[e * N + n0 + gcol];
                    #pragma unroll
                    for (int j = 0; j < 4; j++) {
                        int lr = wr * 128 + mi * 16 + (l >> 4) * 4 + j;
                        float v = acc[mi][ni][j] + bv;
                        if (MODE == 1)
                            v = 0.5f * v * (1.0f + erff(v * 0.70710678118654752f));
                        sl[lr * 136 + lc] = (short)f2bf(v);
                    }
                }
            }
        }
        __syncthreads();
        {
            const int rr = tid >> 4;        // [0,32)
            const int cc = tid & 15;        // [0,16) 16B chunks in 128-col half
            #pragma unroll
            for (int p = 0; p < 8; p++) {
                int lr = p * 32 + rr;       // [0,256)
                short8v v = *(const short8v*)&sl[lr * 136 + cc * 8];
                *(short8v*)(Cout + (size_t)(row_base + lr) * N + n0 + h * 128 + cc * 8) = v;
            }
        }
        __syncthreads();
    }
}

// ---------------- combine: out = x + w0*O[p0] + w1*O[p1] ----------------
__global__ void combine_kernel(const float* __restrict__ x,
                               const int* __restrict__ tok_pos,
                               const float* __restrict__ tok_w,
                               const unsigned short* __restrict__ obuf,
                               float* __restrict__ out) {
    const int wave = threadIdx.x >> 6;
    const int lane = threadIdx.x & 63;
    const int t = blockIdx.x * 4 + wave;
    int2 pp = ((const int2*)tok_pos)[t];
    float2 ww = ((const float2*)tok_w)[t];
    const float4* xr = (const float4*)(x + (size_t)t * D_MODEL);
    float4* orow = (float4*)(out + (size_t)t * D_MODEL);
    const short4* o0 = (const short4*)(obuf + (size_t)pp.x * D_MODEL);
    const short4* o1 = (const short4*)(obuf + (size_t)pp.y * D_MODEL);
    #pragma unroll
    for (int j = 0; j < 4; j++) {
        int idx = j * 64 + lane;
        float4 xv = xr[idx];
        short4 a = o0[idx];
        short4 b = o1[idx];
        float4 r;
        r.x = xv.x + ww.x * bf2f((unsigned short)a.x) + ww.y * bf2f((unsigned short)b.x);
        r.y = xv.y + ww.x * bf2f((unsigned short)a.y) + ww.y * bf2f((unsigned short)b.y);
        r.z = xv.z + ww.x * bf2f((unsigned short)a.z) + ww.y * bf2f((unsigned short)b.z);
        r.w = xv.w + ww.x * bf2f((unsigned short)a.w) + ww.y * bf2f((unsigned short)b.w);
        orow[idx] = r;
    }
}

// ---------------- launch ----------------
extern "C" void kernel_launch(void* const* d_in, const int* in_sizes, int n_in,
                              void* d_out, int out_size, void* d_ws, size_t ws_size,
                              hipStream_t stream) {
    const float* x  = (const float*)d_in[0];
    const float* nw = (const float*)d_in[1];
    const float* gw = (const float*)d_in[2];
    const float* w1 = (const float*)d_in[3];
    const float* b1 = (const float*)d_in[4];
    const float* w2 = (const float*)d_in[5];
    const float* b2 = (const float*)d_in[6];
    float* out = (float*)d_out;
    char* ws = (char*)d_ws;

    size_t off = 0;
    unsigned short* tb   = (unsigned short*)(ws + off); off += (size_t)T_TOK * D_MODEL * 2;
    unsigned short* w1b  = (unsigned short*)(ws + off); off += (size_t)N_EXP * HIDDEN * D_MODEL * 2;
    unsigned short* w2b  = (unsigned short*)(ws + off); off += (size_t)N_EXP * D_MODEL * HIDDEN * 2;
    unsigned short* h    = (unsigned short*)(ws + off); off += (size_t)MAXPOS * HIDDEN * 2;
    unsigned short* obuf = (unsigned short*)(ws + off); off += (size_t)MAXPOS * D_MODEL * 2;
    int*   perm_tok = (int*)(ws + off);   off += MAXPOS * 4;
    int*   tok_e    = (int*)(ws + off);   off += T_TOK * 2 * 4;
    float* tok_w    = (float*)(ws + off); off += T_TOK * 2 * 4;
    int*   tok_pos  = (int*)(ws + off);   off += T_TOK * 2 * 4;
    int*   meta     = (int*)(ws + off);
    int* counts  = meta;
    int* pos_ctr = meta + 8;
    int* poff    = meta + 16;

    hipMemsetAsync(meta, 0, 32, stream);

    rms_gate_kernel<<<T_TOK / 4, 256, 0, stream>>>(x, nw, gw, tb, tok_e, tok_w);

    const int n4 = N_EXP * HIDDEN * D_MODEL / 4;
    cvt_bf16_kernel<<<n4 / 256, 256, 0, stream>>>((const float4*)w1, (ushort4*)w1b, n4);
    cvt_bf16_kernel<<<n4 / 256, 256, 0, stream>>>((const float4*)w2, (ushort4*)w2b, n4);

    hist_kernel<<<32, 256, 0, stream>>>(tok_e, counts);
    scan_fill_kernel<<<MAXPOS / 256, 256, 0, stream>>>(perm_tok, counts, poff, pos_ctr);
    scatter_kernel<<<T_TOK / 256, 256, 0, stream>>>(tok_e, poff, pos_ctr, perm_tok, tok_pos);

    moe_gemm_kernel<1, D_MODEL, HIDDEN><<<ROWT * (HIDDEN / 256), 512, 0, stream>>>(
        tb, w1b, b1, perm_tok, poff, h);
    moe_gemm_kernel<2, HIDDEN, D_MODEL><<<ROWT * (D_MODEL / 256), 512, 0, stream>>>(
        h, w2b, b2, perm_tok, poff, obuf);

    combine_kernel<<<T_TOK / 4, 256, 0, stream>>>(x, tok_pos, tok_w, obuf, out);
}